// Round 1
// baseline (449.635 us; speedup 1.0000x reference)
//
#include <hip/hip_runtime.h>
#include <stdint.h>

// ---------------- problem constants ----------------
#define CIN   256
#define COUT  256
#define HH    56
#define WW    56
#define HW    3136          // 56*56
#define BATCH 32
#define NPIX  (BATCH*HW)    // 100352 = 784 * 128 exactly (no tail tiles!)
#define PH    58
#define PW    58
#define PPIX  (PH*PW)       // 3364
#define KTOT  2304          // 9 taps * 256 cin
#define BKK   64
#define NKIT  (KTOT/BKK)    // 36

typedef _Float16 f16;
typedef _Float16 half8  __attribute__((ext_vector_type(8)));
typedef float    floatx4 __attribute__((ext_vector_type(4)));

// -------- global->LDS 16B async copy (wave-uniform LDS base + lane*16) ------
__device__ static inline void gload_lds16(const void* g, void* lds_wave_uniform_base) {
#if __has_builtin(__builtin_amdgcn_global_load_lds)
    __builtin_amdgcn_global_load_lds(
        (const __attribute__((address_space(1))) void*)g,
        (__attribute__((address_space(3))) void*)lds_wave_uniform_base,
        16, 0, 0);
#else
    // fallback: per-lane VGPR round-trip (slower but correct)
    int lane = threadIdx.x & 63;
    *(half8*)((char*)lds_wave_uniform_base + lane * 16) = *(const half8*)g;
#endif
}

// ---------------------------------------------------------------------------
// Kernel 1: weight prep. scale[o] = mean(|w[o]|); wg[o][t*256+i] = sign(w[o][i][t])
// Also zero-inits the BN-stat accumulators (ws is poisoned each launch).
// ---------------------------------------------------------------------------
__global__ __launch_bounds__(256) void prep_w(const float* __restrict__ w,
                                              f16* __restrict__ wg,
                                              float* __restrict__ scale,
                                              float* __restrict__ bnsum,
                                              float* __restrict__ bnsumsq) {
    int o = blockIdx.x;
    int i = threadIdx.x;
    const float* wrow = w + (size_t)o * KTOT + (size_t)i * 9;   // OIHW: [o][i][3][3]
    float asum = 0.f;
#pragma unroll
    for (int t = 0; t < 9; ++t) {
        float v = wrow[t];
        asum += fabsf(v);
        f16 s = (v > 0.f) ? (f16)1.f : ((v < 0.f) ? (f16)(-1.f) : (f16)0.f);
        wg[(size_t)o * KTOT + t * CIN + i] = s;   // K-order: k = t*256 + i
    }
    for (int off = 32; off > 0; off >>= 1) asum += __shfl_down(asum, off);
    __shared__ float red[4];
    if ((threadIdx.x & 63) == 0) red[threadIdx.x >> 6] = asum;
    __syncthreads();
    if (threadIdx.x == 0) {
        scale[o]   = (red[0] + red[1] + red[2] + red[3]) * (1.f / (float)KTOT);
        bnsum[o]   = 0.f;
        bnsumsq[o] = 0.f;
    }
}

// ---------------------------------------------------------------------------
// Kernel 2: zero the 1-pixel border of the padded NHWC sign tensor.
// ---------------------------------------------------------------------------
__global__ __launch_bounds__(256) void zero_border(f16* __restrict__ xs) {
    int n  = blockIdx.x / PH;
    int pr = blockIdx.x % PH;
    f16* row = xs + ((size_t)n * PPIX + (size_t)pr * PW) * CIN;
    if (pr == 0 || pr == PH - 1) {
        for (int idx = threadIdx.x; idx < PW * CIN; idx += 256) row[idx] = (f16)0.f;
    } else {
        row[threadIdx.x] = (f16)0.f;                     // col 0
        row[(PW - 1) * CIN + threadIdx.x] = (f16)0.f;    // col 57
    }
}

// ---------------------------------------------------------------------------
// Kernel 3: binarize + NCHW->padded-NHWC transpose.
// grid (49, 4, 32): 64-pixel x 64-cin tiles per image.
// ---------------------------------------------------------------------------
__global__ __launch_bounds__(256) void binarize(const float* __restrict__ x,
                                                f16* __restrict__ xs) {
    __shared__ f16 lds[64 * 66];   // [cin][pix], stride 66 halves -> +33 dwords/row
    int p0 = blockIdx.x * 64;
    int c0 = blockIdx.y * 64;
    int n  = blockIdx.z;
    const float* xin = x + (size_t)n * CIN * HW;
    int t = threadIdx.x;
    int colp = t & 63;
    int rowq = t >> 6;
#pragma unroll
    for (int r = 0; r < 16; ++r) {
        int ci = r * 4 + rowq;
        float v = xin[(size_t)(c0 + ci) * HW + p0 + colp];
        lds[ci * 66 + colp] = (v > 0.f) ? (f16)1.f : ((v < 0.f) ? (f16)(-1.f) : (f16)0.f);
    }
    __syncthreads();
    int cl = t & 63;
#pragma unroll
    for (int r = 0; r < 16; ++r) {
        int pi = r * 4 + rowq;
        int p  = p0 + pi;
        int h  = p / WW, w = p - (p / WW) * WW;
        // padded coords (h+1, w+1)
        xs[((size_t)n * PPIX + (size_t)(h + 1) * PW + (w + 1)) * CIN + c0 + cl] =
            lds[cl * 66 + pi];
    }
}

// ---------------------------------------------------------------------------
// Kernel 4: binary conv as implicit GEMM (m97 structure).
// D[m=pixel][o=cout], A[m][k] = xs[n, h+r, w+s, i], B^T[o][k] = wg.
// grid (784, 2), 256 threads = 4 waves, 128x128 tile, BK=64.
// Epilogue: y=int16 counts + per-channel atomic sum/sumsq.
// ---------------------------------------------------------------------------
__global__ __launch_bounds__(256) void conv_gemm(const f16* __restrict__ xs,
                                                 const f16* __restrict__ wg,
                                                 short* __restrict__ y,
                                                 float* __restrict__ bnsum,
                                                 float* __restrict__ bnsumsq) {
    __shared__ __align__(16) f16 As[128 * BKK];   // [pixel][k_local] 16 KB
    __shared__ __align__(16) f16 Bs[128 * BKK];   // [cout ][k_local] 16 KB
    int tid  = threadIdx.x;
    int lane = tid & 63;
    int wv   = tid >> 6;
    int wm   = wv & 1;        // wave row (pixels)
    int wn   = wv >> 1;       // wave col (couts)
    int mt   = blockIdx.x;
    int nt   = blockIdx.y;

    // staging source bases: thread covers pixels/couts {tid>>3 + 32j}, k-chunk (tid&7)*8
    const f16* aBase[4];
    const f16* bBase[4];
    int prow = tid >> 3;
    int koff = (tid & 7) * 8;
#pragma unroll
    for (int j = 0; j < 4; ++j) {
        int P = mt * 128 + prow + 32 * j;     // global pixel, < 100352 always
        int n = P / HW;
        int p = P - n * HW;
        int h = p / WW;
        int w = p - h * WW;
        aBase[j] = xs + ((size_t)n * PPIX + (size_t)h * PW + w) * CIN + koff;
        int o = nt * 128 + prow + 32 * j;
        bBase[j] = wg + (size_t)o * KTOT + koff;
    }

    floatx4 zero4 = {0.f, 0.f, 0.f, 0.f};
    floatx4 acc[4][4];
#pragma unroll
    for (int im = 0; im < 4; ++im)
#pragma unroll
        for (int in = 0; in < 4; ++in) acc[im][in] = zero4;

    for (int kb = 0; kb < NKIT; ++kb) {
        int t9 = kb >> 2;                  // tap 0..8 (4 K-iters per tap)
        int r  = (t9 * 11) >> 5;           // t9/3 for t9 in [0,9)
        int s  = t9 - r * 3;
        int aoff = (r * PW + s) * CIN + (kb & 3) * 64;
        int boff = kb * BKK;
#pragma unroll
        for (int j = 0; j < 4; ++j)
            gload_lds16(aBase[j] + aoff, &As[j * 2048 + wv * 512]);
#pragma unroll
        for (int j = 0; j < 4; ++j)
            gload_lds16(bBase[j] + boff, &Bs[j * 2048 + wv * 512]);
        __syncthreads();

#pragma unroll
        for (int kk = 0; kk < 2; ++kk) {
            half8 af[4], bf[4];
            int krow = kk * 32 + (lane >> 4) * 8;
#pragma unroll
            for (int im = 0; im < 4; ++im)
                af[im] = *(const half8*)&As[(wm * 64 + im * 16 + (lane & 15)) * BKK + krow];
#pragma unroll
            for (int in = 0; in < 4; ++in)
                bf[in] = *(const half8*)&Bs[(wn * 64 + in * 16 + (lane & 15)) * BKK + krow];
#pragma unroll
            for (int im = 0; im < 4; ++im)
#pragma unroll
                for (int in = 0; in < 4; ++in)
                    acc[im][in] = __builtin_amdgcn_mfma_f32_16x16x32_f16(
                        af[im], bf[in], acc[im][in], 0, 0, 0);
        }
        __syncthreads();
    }

    // epilogue: C/D layout col=lane&15, row=(lane>>4)*4+reg  [guide §3, m89-verified]
    int colBase = nt * 128 + wn * 64 + (lane & 15);
    int rowBase = mt * 128 + wm * 64 + (lane >> 4) * 4;
#pragma unroll
    for (int in = 0; in < 4; ++in) {
        int o = colBase + in * 16;
        float s1 = 0.f, s2 = 0.f;
#pragma unroll
        for (int im = 0; im < 4; ++im) {
            int m0 = rowBase + im * 16;
#pragma unroll
            for (int rg = 0; rg < 4; ++rg) {
                float v = acc[im][in][rg];              // exact integer count
                y[(size_t)(m0 + rg) * COUT + o] = (short)__float2int_rn(v);
                s1 += v;
                s2 += v * v;
            }
        }
        // reduce over the 4 quad-groups (lanes sharing lane&15)
        s1 += __shfl_xor(s1, 16); s2 += __shfl_xor(s2, 16);
        s1 += __shfl_xor(s1, 32); s2 += __shfl_xor(s2, 32);
        if ((lane >> 4) == 0) {
            atomicAdd(&bnsum[o], s1);
            atomicAdd(&bnsumsq[o], s2);
        }
    }
}

// ---------------------------------------------------------------------------
// Kernel 5: fold BN into per-channel (g, c): out = relu(g*s + c)
// y_real = scale*s; mean_r = scale*mean_s; var_r = scale^2*var_s
// ---------------------------------------------------------------------------
__global__ void coeff(const float* __restrict__ bnsum, const float* __restrict__ bnsumsq,
                      const float* __restrict__ scale, const float* __restrict__ gamma,
                      const float* __restrict__ beta, float* __restrict__ kg,
                      float* __restrict__ kc) {
    int o = threadIdx.x;
    float mean = bnsum[o] * (1.f / (float)NPIX);
    float var  = fmaxf(bnsumsq[o] * (1.f / (float)NPIX) - mean * mean, 0.f);
    float sc   = scale[o];
    float inv  = rsqrtf(sc * sc * var + 1e-5f);
    float g    = gamma[o] * sc * inv;
    kg[o] = g;
    kc[o] = beta[o] - mean * g;
}

// ---------------------------------------------------------------------------
// Kernel 6: int16 NHWC -> fp32 NCHW transpose + affine + relu.
// grid (49, 4, 32): 64-pixel x 64-cout tiles.
// ---------------------------------------------------------------------------
__global__ __launch_bounds__(256) void bn_out(const short* __restrict__ y,
                                              const float* __restrict__ kg,
                                              const float* __restrict__ kc,
                                              float* __restrict__ out) {
    __shared__ float lds[64 * 65];
    int p0 = blockIdx.x * 64;
    int o0 = blockIdx.y * 64;
    int n  = blockIdx.z;
    int t  = threadIdx.x;
    int ol = t & 63;
    int q  = t >> 6;
    float g = kg[o0 + ol];
    float c = kc[o0 + ol];
    const short* yb = y + ((size_t)n * HW + p0) * COUT + o0;
#pragma unroll
    for (int r = 0; r < 16; ++r) {
        int pi = r * 4 + q;
        float v = (float)yb[(size_t)pi * COUT + ol];
        lds[ol * 65 + pi] = fmaxf(g * v + c, 0.f);
    }
    __syncthreads();
    float* ob = out + ((size_t)n * COUT + o0) * HW + p0;
    int pl = t & 63;
#pragma unroll
    for (int r = 0; r < 16; ++r) {
        int oi = r * 4 + q;
        ob[(size_t)oi * HW + pl] = lds[oi * 65 + pl];
    }
}

// ---------------------------------------------------------------------------
extern "C" void kernel_launch(void* const* d_in, const int* in_sizes, int n_in,
                              void* d_out, int out_size, void* d_ws, size_t ws_size,
                              hipStream_t stream) {
    const float* x     = (const float*)d_in[0];   // [32,256,56,56]
    const float* w     = (const float*)d_in[1];   // [256,256,3,3]
    const float* gamma = (const float*)d_in[2];   // [256]
    const float* beta  = (const float*)d_in[3];   // [256]
    float* out = (float*)d_out;

    char* ws = (char*)d_ws;
    size_t off = 0;
    f16* xs = (f16*)(ws + off);   off += (size_t)BATCH * PPIX * CIN * sizeof(f16); // 55.1 MB
    f16* wg = (f16*)(ws + off);   off += (size_t)COUT * KTOT * sizeof(f16);        // 1.18 MB
    short* y = (short*)(ws + off); off += (size_t)NPIX * COUT * sizeof(short);     // 51.4 MB
    float* scale   = (float*)(ws + off); off += 1024;
    float* bnsum   = (float*)(ws + off); off += 1024;
    float* bnsumsq = (float*)(ws + off); off += 1024;
    float* kg      = (float*)(ws + off); off += 1024;
    float* kc      = (float*)(ws + off); off += 1024;

    hipLaunchKernelGGL(prep_w, dim3(COUT), dim3(256), 0, stream, w, wg, scale, bnsum, bnsumsq);
    hipLaunchKernelGGL(zero_border, dim3(BATCH * PH), dim3(256), 0, stream, xs);
    hipLaunchKernelGGL(binarize, dim3(HW / 64, CIN / 64, BATCH), dim3(256), 0, stream, x, xs);
    hipLaunchKernelGGL(conv_gemm, dim3(NPIX / 128, 2), dim3(256), 0, stream,
                       xs, wg, y, bnsum, bnsumsq);
    hipLaunchKernelGGL(coeff, dim3(1), dim3(256), 0, stream,
                       bnsum, bnsumsq, scale, gamma, beta, kg, kc);
    hipLaunchKernelGGL(bn_out, dim3(HW / 64, COUT / 64, BATCH), dim3(256), 0, stream,
                       y, kg, kc, out);
}

// Round 2
// 419.259 us; speedup vs baseline: 1.0724x; 1.0724x over previous
//
#include <hip/hip_runtime.h>
#include <stdint.h>

// ---------------- problem constants ----------------
#define CIN   256
#define COUT  256
#define HH    56
#define WW    56
#define HW    3136          // 56*56
#define BATCH 32
#define NPIX  (BATCH*HW)    // 100352 = 784 * 128 exactly (no tail tiles!)
#define PH    58
#define PW    58
#define PPIX  (PH*PW)       // 3364
#define KTOT  2304          // 9 taps * 256 cin
#define BKK   64
#define NKIT  (KTOT/BKK)    // 36

typedef _Float16 f16;
typedef _Float16 half8  __attribute__((ext_vector_type(8)));
typedef short    short8 __attribute__((ext_vector_type(8)));
typedef float    floatx4 __attribute__((ext_vector_type(4)));

// -------- global->LDS 16B async copy (wave-uniform LDS base + lane*16) ------
__device__ static inline void gload_lds16(const void* g, void* lds_wave_uniform_base) {
#if __has_builtin(__builtin_amdgcn_global_load_lds)
    __builtin_amdgcn_global_load_lds(
        (const __attribute__((address_space(1))) void*)g,
        (__attribute__((address_space(3))) void*)lds_wave_uniform_base,
        16, 0, 0);
#else
    int lane = threadIdx.x & 63;
    *(half8*)((char*)lds_wave_uniform_base + lane * 16) = *(const half8*)g;
#endif
}

// ---------------------------------------------------------------------------
// Kernel 1: weight prep. scale[o] = mean(|w[o]|); wg[o][t*256+i] = sign(w[o][i][t])
// Also zero-inits the BN-stat accumulators (ws is poisoned each launch).
// ---------------------------------------------------------------------------
__global__ __launch_bounds__(256) void prep_w(const float* __restrict__ w,
                                              f16* __restrict__ wg,
                                              float* __restrict__ scale,
                                              float* __restrict__ bnsum,
                                              float* __restrict__ bnsumsq) {
    int o = blockIdx.x;
    int i = threadIdx.x;
    const float* wrow = w + (size_t)o * KTOT + (size_t)i * 9;   // OIHW: [o][i][3][3]
    float asum = 0.f;
#pragma unroll
    for (int t = 0; t < 9; ++t) {
        float v = wrow[t];
        asum += fabsf(v);
        f16 s = (v > 0.f) ? (f16)1.f : ((v < 0.f) ? (f16)(-1.f) : (f16)0.f);
        wg[(size_t)o * KTOT + t * CIN + i] = s;   // K-order: k = t*256 + i
    }
    for (int off = 32; off > 0; off >>= 1) asum += __shfl_down(asum, off);
    __shared__ float red[4];
    if ((threadIdx.x & 63) == 0) red[threadIdx.x >> 6] = asum;
    __syncthreads();
    if (threadIdx.x == 0) {
        scale[o]   = (red[0] + red[1] + red[2] + red[3]) * (1.f / (float)KTOT);
        bnsum[o]   = 0.f;
        bnsumsq[o] = 0.f;
    }
}

// ---------------------------------------------------------------------------
// Kernel 2: zero the 1-pixel border of the padded NHWC sign tensor.
// ---------------------------------------------------------------------------
__global__ __launch_bounds__(256) void zero_border(f16* __restrict__ xs) {
    int n  = blockIdx.x / PH;
    int pr = blockIdx.x % PH;
    f16* row = xs + ((size_t)n * PPIX + (size_t)pr * PW) * CIN;
    if (pr == 0 || pr == PH - 1) {
        for (int idx = threadIdx.x; idx < PW * CIN; idx += 256) row[idx] = (f16)0.f;
    } else {
        row[threadIdx.x] = (f16)0.f;                     // col 0
        row[(PW - 1) * CIN + threadIdx.x] = (f16)0.f;    // col 57
    }
}

// ---------------------------------------------------------------------------
// Kernel 3: binarize + NCHW->padded-NHWC transpose.
// grid (49, 4, 32): 64-pixel x 64-cin tiles per image.
// Phase 2 assembles half8 -> 16B global stores.
// ---------------------------------------------------------------------------
__global__ __launch_bounds__(256) void binarize(const float* __restrict__ x,
                                                f16* __restrict__ xs) {
    __shared__ f16 lds[64 * 66];   // [cin][pix], stride 66 halves
    int p0 = blockIdx.x * 64;
    int c0 = blockIdx.y * 64;
    int n  = blockIdx.z;
    const float* xin = x + (size_t)n * CIN * HW;
    int t = threadIdx.x;
    int colp = t & 63;
    int rowq = t >> 6;
#pragma unroll
    for (int r = 0; r < 16; ++r) {
        int ci = r * 4 + rowq;
        float v = xin[(size_t)(c0 + ci) * HW + p0 + colp];
        lds[ci * 66 + colp] = (v > 0.f) ? (f16)1.f : ((v < 0.f) ? (f16)(-1.f) : (f16)0.f);
    }
    __syncthreads();
    int cch = t & 7;
#pragma unroll
    for (int j = 0; j < 2; ++j) {
        int pi = (t >> 3) + 32 * j;
        int p  = p0 + pi;
        int h  = p / WW, w = p - (p / WW) * WW;
        half8 v;
#pragma unroll
        for (int e = 0; e < 8; ++e) v[e] = lds[(cch * 8 + e) * 66 + pi];
        *(half8*)&xs[((size_t)n * PPIX + (size_t)(h + 1) * PW + (w + 1)) * CIN
                     + c0 + cch * 8] = v;
    }
}

// ---------------------------------------------------------------------------
// Kernel 4: binary conv as implicit GEMM (m97 structure) + XOR-swizzled LDS.
// LDS row r stores k-chunk (slot ^ (r&7)) at slot; staging permutes the
// SOURCE address (global_load_lds dest is fixed lane*16), fragment reads
// un-permute. Kills the 16-way ds_read_b128 bank conflict (row stride = 128B).
// ---------------------------------------------------------------------------
__global__ __launch_bounds__(256) void conv_gemm(const f16* __restrict__ xs,
                                                 const f16* __restrict__ wg,
                                                 short* __restrict__ y,
                                                 float* __restrict__ bnsum,
                                                 float* __restrict__ bnsumsq) {
    __shared__ __align__(16) f16 As[128 * BKK];   // [pixel][k_local] 16 KB
    __shared__ __align__(16) f16 Bs[128 * BKK];   // [cout ][k_local] 16 KB
    int tid  = threadIdx.x;
    int lane = tid & 63;
    int wv   = tid >> 6;
    int wm   = wv & 1;        // wave row (pixels)
    int wn   = wv >> 1;       // wave col (couts)
    int mt   = blockIdx.x;
    int nt   = blockIdx.y;

    const f16* aBase[4];
    const f16* bBase[4];
    int prow = tid >> 3;
    // XOR swizzle: thread at (row prow, slot tid&7) loads global k-chunk (tid&7)^(prow&7)
    int koff = ((tid ^ (tid >> 3)) & 7) * 8;
#pragma unroll
    for (int j = 0; j < 4; ++j) {
        int P = mt * 128 + prow + 32 * j;     // global pixel, < 100352 always
        int n = P / HW;
        int p = P - n * HW;
        int h = p / WW;
        int w = p - h * WW;
        aBase[j] = xs + ((size_t)n * PPIX + (size_t)h * PW + w) * CIN + koff;
        int o = nt * 128 + prow + 32 * j;
        bBase[j] = wg + (size_t)o * KTOT + koff;
    }

    floatx4 zero4 = {0.f, 0.f, 0.f, 0.f};
    floatx4 acc[4][4];
#pragma unroll
    for (int im = 0; im < 4; ++im)
#pragma unroll
        for (int in = 0; in < 4; ++in) acc[im][in] = zero4;

    for (int kb = 0; kb < NKIT; ++kb) {
        int t9 = kb >> 2;                  // tap 0..8 (4 K-iters per tap)
        int r  = (t9 * 11) >> 5;           // t9/3 for t9 in [0,9)
        int s  = t9 - r * 3;
        int aoff = (r * PW + s) * CIN + (kb & 3) * 64;
        int boff = kb * BKK;
#pragma unroll
        for (int j = 0; j < 4; ++j)
            gload_lds16(aBase[j] + aoff, &As[j * 2048 + wv * 512]);
#pragma unroll
        for (int j = 0; j < 4; ++j)
            gload_lds16(bBase[j] + boff, &Bs[j * 2048 + wv * 512]);
        __syncthreads();

#pragma unroll
        for (int kk = 0; kk < 2; ++kk) {
            half8 af[4], bf[4];
            int kc = kk * 4 + (lane >> 4);          // k-chunk index 0..7
#pragma unroll
            for (int im = 0; im < 4; ++im) {
                int rA = wm * 64 + im * 16 + (lane & 15);
                af[im] = *(const half8*)&As[rA * BKK + ((kc ^ (rA & 7)) << 3)];
            }
#pragma unroll
            for (int in = 0; in < 4; ++in) {
                int rB = wn * 64 + in * 16 + (lane & 15);
                bf[in] = *(const half8*)&Bs[rB * BKK + ((kc ^ (rB & 7)) << 3)];
            }
#pragma unroll
            for (int im = 0; im < 4; ++im)
#pragma unroll
                for (int in = 0; in < 4; ++in)
                    acc[im][in] = __builtin_amdgcn_mfma_f32_16x16x32_f16(
                        af[im], bf[in], acc[im][in], 0, 0, 0);
        }
        __syncthreads();
    }

    // epilogue: C/D layout col=lane&15, row=(lane>>4)*4+reg  [guide §3, m89-verified]
    int colBase = nt * 128 + wn * 64 + (lane & 15);
    int rowBase = mt * 128 + wm * 64 + (lane >> 4) * 4;
#pragma unroll
    for (int in = 0; in < 4; ++in) {
        int o = colBase + in * 16;
        float s1 = 0.f, s2 = 0.f;
#pragma unroll
        for (int im = 0; im < 4; ++im) {
            int m0 = rowBase + im * 16;
#pragma unroll
            for (int rg = 0; rg < 4; ++rg) {
                float v = acc[im][in][rg];              // exact integer count
                y[(size_t)(m0 + rg) * COUT + o] = (short)__float2int_rn(v);
                s1 += v;
                s2 += v * v;
            }
        }
        s1 += __shfl_xor(s1, 16); s2 += __shfl_xor(s2, 16);
        s1 += __shfl_xor(s1, 32); s2 += __shfl_xor(s2, 32);
        if ((lane >> 4) == 0) {
            atomicAdd(&bnsum[o], s1);
            atomicAdd(&bnsumsq[o], s2);
        }
    }
}

// ---------------------------------------------------------------------------
// Kernel 5: fold BN into per-channel (g, c): out = relu(g*s + c)
// ---------------------------------------------------------------------------
__global__ void coeff(const float* __restrict__ bnsum, const float* __restrict__ bnsumsq,
                      const float* __restrict__ scale, const float* __restrict__ gamma,
                      const float* __restrict__ beta, float* __restrict__ kg,
                      float* __restrict__ kc) {
    int o = threadIdx.x;
    float mean = bnsum[o] * (1.f / (float)NPIX);
    float var  = fmaxf(bnsumsq[o] * (1.f / (float)NPIX) - mean * mean, 0.f);
    float sc   = scale[o];
    float inv  = rsqrtf(sc * sc * var + 1e-5f);
    float g    = gamma[o] * sc * inv;
    kg[o] = g;
    kc[o] = beta[o] - mean * g;
}

// ---------------------------------------------------------------------------
// Kernel 6: int16 NHWC -> fp32 NCHW transpose + affine + relu.
// Phase 1: short8 16B loads; phase 2: float4 16B stores.
// LDS stride 65 floats: both phases verified conflict-free.
// ---------------------------------------------------------------------------
__global__ __launch_bounds__(256) void bn_out(const short* __restrict__ y,
                                              const float* __restrict__ kg,
                                              const float* __restrict__ kc,
                                              float* __restrict__ out) {
    __shared__ float lds[64 * 65];   // [pix][ch], stride 65
    int p0 = blockIdx.x * 64;
    int o0 = blockIdx.y * 64;
    int n  = blockIdx.z;
    int t  = threadIdx.x;
    int cch = t & 7;
    float g[8], c[8];
#pragma unroll
    for (int e = 0; e < 8; ++e) {
        g[e] = kg[o0 + cch * 8 + e];
        c[e] = kc[o0 + cch * 8 + e];
    }
    const short* yb = y + ((size_t)n * HW + p0) * COUT + o0;
#pragma unroll
    for (int j = 0; j < 2; ++j) {
        int pi = (t >> 3) + 32 * j;
        short8 sv = *(const short8*)&yb[(size_t)pi * COUT + cch * 8];
#pragma unroll
        for (int e = 0; e < 8; ++e)
            lds[pi * 65 + cch * 8 + e] = fmaxf(g[e] * (float)sv[e] + c[e], 0.f);
    }
    __syncthreads();
    float* ob = out + ((size_t)n * COUT + o0) * HW + p0;
    int pq = t & 15;       // 16 float4 = 64 pixels
    int ch = t >> 4;       // 16 channels per round
#pragma unroll
    for (int r = 0; r < 4; ++r) {
        int cr = ch + 16 * r;
        floatx4 v;
#pragma unroll
        for (int e = 0; e < 4; ++e) v[e] = lds[(pq * 4 + e) * 65 + cr];
        *(floatx4*)&ob[(size_t)cr * HW + pq * 4] = v;
    }
}

// ---------------------------------------------------------------------------
extern "C" void kernel_launch(void* const* d_in, const int* in_sizes, int n_in,
                              void* d_out, int out_size, void* d_ws, size_t ws_size,
                              hipStream_t stream) {
    const float* x     = (const float*)d_in[0];   // [32,256,56,56]
    const float* w     = (const float*)d_in[1];   // [256,256,3,3]
    const float* gamma = (const float*)d_in[2];   // [256]
    const float* beta  = (const float*)d_in[3];   // [256]
    float* out = (float*)d_out;

    char* ws = (char*)d_ws;
    size_t off = 0;
    f16* xs = (f16*)(ws + off);   off += (size_t)BATCH * PPIX * CIN * sizeof(f16); // 55.1 MB
    f16* wg = (f16*)(ws + off);   off += (size_t)COUT * KTOT * sizeof(f16);        // 1.18 MB
    short* y = (short*)(ws + off); off += (size_t)NPIX * COUT * sizeof(short);     // 51.4 MB
    float* scale   = (float*)(ws + off); off += 1024;
    float* bnsum   = (float*)(ws + off); off += 1024;
    float* bnsumsq = (float*)(ws + off); off += 1024;
    float* kg      = (float*)(ws + off); off += 1024;
    float* kc      = (float*)(ws + off); off += 1024;

    hipLaunchKernelGGL(prep_w, dim3(COUT), dim3(256), 0, stream, w, wg, scale, bnsum, bnsumsq);
    hipLaunchKernelGGL(zero_border, dim3(BATCH * PH), dim3(256), 0, stream, xs);
    hipLaunchKernelGGL(binarize, dim3(HW / 64, CIN / 64, BATCH), dim3(256), 0, stream, x, xs);
    hipLaunchKernelGGL(conv_gemm, dim3(NPIX / 128, 2), dim3(256), 0, stream,
                       xs, wg, y, bnsum, bnsumsq);
    hipLaunchKernelGGL(coeff, dim3(1), dim3(256), 0, stream,
                       bnsum, bnsumsq, scale, gamma, beta, kg, kc);
    hipLaunchKernelGGL(bn_out, dim3(HW / 64, COUT / 64, BATCH), dim3(256), 0, stream,
                       y, kg, kc, out);
}

// Round 3
// 334.951 us; speedup vs baseline: 1.3424x; 1.2517x over previous
//
#include <hip/hip_runtime.h>
#include <stdint.h>

// ---------------- problem constants ----------------
#define CIN   256
#define COUT  256
#define HH    56
#define WW    56
#define HW    3136          // 56*56
#define BATCH 32
#define NPIX  (BATCH*HW)    // 100352 = 784 * 128 exactly
#define PH    58
#define PW    58
#define PPIX  (PH*PW)       // 3364
#define KTOT  2304          // 9 taps * 256 cin
#define BKB   128           // K-block in bytes (i8 elems) = half a tap
#define NKIT  (KTOT/BKB)    // 18

typedef int8_t  i8;
typedef int     intx4  __attribute__((ext_vector_type(4)));
typedef int8_t  i8x16  __attribute__((ext_vector_type(16)));
typedef short   short8 __attribute__((ext_vector_type(8)));
typedef float   floatx4 __attribute__((ext_vector_type(4)));

// -------- global->LDS 16B async copy (wave-uniform LDS base + lane*16) ------
__device__ static inline void gload_lds16(const void* g, void* lds_wave_uniform_base) {
#if __has_builtin(__builtin_amdgcn_global_load_lds)
    __builtin_amdgcn_global_load_lds(
        (const __attribute__((address_space(1))) void*)g,
        (__attribute__((address_space(3))) void*)lds_wave_uniform_base,
        16, 0, 0);
#else
    int lane = threadIdx.x & 63;
    *(i8x16*)((char*)lds_wave_uniform_base + lane * 16) = *(const i8x16*)g;
#endif
}

// ---------------------------------------------------------------------------
// Kernel 1: weight prep. scale[o]=mean|w[o]|; wg[o][t*256+i]=sign(w) as int8.
// Also zero-inits BN-stat accumulators (ws is poisoned each launch).
// ---------------------------------------------------------------------------
__global__ __launch_bounds__(256) void prep_w(const float* __restrict__ w,
                                              i8* __restrict__ wg,
                                              float* __restrict__ scale,
                                              float* __restrict__ bnsum,
                                              float* __restrict__ bnsumsq) {
    int o = blockIdx.x;
    int i = threadIdx.x;
    const float* wrow = w + (size_t)o * KTOT + (size_t)i * 9;   // OIHW
    float asum = 0.f;
#pragma unroll
    for (int t = 0; t < 9; ++t) {
        float v = wrow[t];
        asum += fabsf(v);
        wg[(size_t)o * KTOT + t * CIN + i] = (v > 0.f) ? (i8)1 : ((v < 0.f) ? (i8)(-1) : (i8)0);
    }
    for (int off = 32; off > 0; off >>= 1) asum += __shfl_down(asum, off);
    __shared__ float red[4];
    if ((threadIdx.x & 63) == 0) red[threadIdx.x >> 6] = asum;
    __syncthreads();
    if (threadIdx.x == 0) {
        scale[o]   = (red[0] + red[1] + red[2] + red[3]) * (1.f / (float)KTOT);
        bnsum[o]   = 0.f;
        bnsumsq[o] = 0.f;
    }
}

// ---------------------------------------------------------------------------
// Kernel 2: zero the 1-pixel border of the padded NHWC int8 sign tensor.
// ---------------------------------------------------------------------------
__global__ __launch_bounds__(256) void zero_border(i8* __restrict__ xs) {
    int n  = blockIdx.x / PH;
    int pr = blockIdx.x % PH;
    int* row = (int*)(xs + ((size_t)n * PPIX + (size_t)pr * PW) * CIN);
    if (pr == 0 || pr == PH - 1) {
        for (int idx = threadIdx.x; idx < PW * CIN / 4; idx += 256) row[idx] = 0;
    } else {
        if (threadIdx.x < 64)       row[threadIdx.x] = 0;                       // col 0
        else if (threadIdx.x < 128) row[(PW - 1) * (CIN / 4) + threadIdx.x - 64] = 0; // col 57
    }
}

// ---------------------------------------------------------------------------
// Kernel 3: binarize + NCHW->padded-NHWC transpose, int8 out.
// grid (49, 4, 32): 64-pixel x 64-cin tiles.
// LDS layout [pix][cin/4] as dwords (stride 17 dwords): phase1 packs 4 cin
// into one dword per pixel; phase2 emits 16B int8 stores. Both phases <=2-way
// bank aliasing (free).
// ---------------------------------------------------------------------------
__global__ __launch_bounds__(256) void binarize(const float* __restrict__ x,
                                                i8* __restrict__ xs) {
    __shared__ int lds[64 * 17];   // [pix][cinquad], stride 17 dwords
    int p0 = blockIdx.x * 64;
    int c0 = blockIdx.y * 64;
    int n  = blockIdx.z;
    const float* xin = x + (size_t)n * CIN * HW;
    int t   = threadIdx.x;
    int pix = t & 63;
    // phase 1: each thread packs 4 cin (one quad) for one pixel
#pragma unroll
    for (int r = 0; r < 4; ++r) {
        int cq = (t >> 6) + 4 * r;            // cin quad 0..15
        int packed = 0;
#pragma unroll
        for (int e = 0; e < 4; ++e) {
            float v = xin[(size_t)(c0 + cq * 4 + e) * HW + p0 + pix];
            int s = (v > 0.f) ? 1 : ((v < 0.f) ? -1 : 0);
            packed |= (s & 0xff) << (8 * e);
        }
        lds[pix * 17 + cq] = packed;
    }
    __syncthreads();
    // phase 2: each thread stores 16 cin-contiguous bytes for one pixel
    int cch = t & 3;                           // 16-byte chunk 0..3
    int pi  = t >> 2;                          // pixel 0..63
    int4 v;
    v.x = lds[pi * 17 + cch * 4 + 0];
    v.y = lds[pi * 17 + cch * 4 + 1];
    v.z = lds[pi * 17 + cch * 4 + 2];
    v.w = lds[pi * 17 + cch * 4 + 3];
    int p = p0 + pi;
    int h = p / WW, w = p - (p / WW) * WW;
    *(int4*)&xs[((size_t)n * PPIX + (size_t)(h + 1) * PW + (w + 1)) * CIN
                + c0 + cch * 16] = v;
}

// ---------------------------------------------------------------------------
// Kernel 4: binary conv as implicit GEMM, int8 MFMA (K=64), BK=128 bytes.
// grid (784, 2), 256 threads = 4 waves, 128x128 tile, 18 K-iterations.
// XOR-swizzled LDS k-chunks (source-permuted for global_load_lds).
// Epilogue: y=int16 exact counts + per-channel atomic sum/sumsq (fp32).
// ---------------------------------------------------------------------------
__global__ __launch_bounds__(256) void conv_gemm(const i8* __restrict__ xs,
                                                 const i8* __restrict__ wg,
                                                 short* __restrict__ y,
                                                 float* __restrict__ bnsum,
                                                 float* __restrict__ bnsumsq) {
    __shared__ __align__(16) i8 As[128 * BKB];   // [pixel][k_local] 16 KB
    __shared__ __align__(16) i8 Bs[128 * BKB];   // [cout ][k_local] 16 KB
    int tid  = threadIdx.x;
    int lane = tid & 63;
    int wv   = tid >> 6;
    int wm   = wv & 1;        // wave row (pixels)
    int wn   = wv >> 1;       // wave col (couts)
    int mt   = blockIdx.x;
    int nt   = blockIdx.y;

    const i8* aBase[4];
    const i8* bBase[4];
    int prow = tid >> 3;
    // XOR swizzle: thread at (row prow, slot tid&7) loads global 16B-chunk (tid&7)^(prow&7)
    int koff = ((tid ^ (tid >> 3)) & 7) * 16;
#pragma unroll
    for (int j = 0; j < 4; ++j) {
        int P = mt * 128 + prow + 32 * j;     // global pixel, < 100352 always
        int n = P / HW;
        int p = P - n * HW;
        int h = p / WW;
        int w = p - h * WW;
        aBase[j] = xs + ((size_t)n * PPIX + (size_t)h * PW + w) * CIN + koff;
        int o = nt * 128 + prow + 32 * j;
        bBase[j] = wg + (size_t)o * KTOT + koff;
    }

    intx4 zero4 = {0, 0, 0, 0};
    intx4 acc[4][4];
#pragma unroll
    for (int im = 0; im < 4; ++im)
#pragma unroll
        for (int in = 0; in < 4; ++in) acc[im][in] = zero4;

    for (int kb = 0; kb < NKIT; ++kb) {
        int t9 = kb >> 1;                  // tap 0..8 (2 K-iters per tap)
        int r  = (t9 * 11) >> 5;           // t9/3 for t9 in [0,9)
        int s  = t9 - r * 3;
        int aoff = (r * PW + s) * CIN + (kb & 1) * 128;
        int boff = kb * BKB;
#pragma unroll
        for (int j = 0; j < 4; ++j)
            gload_lds16(aBase[j] + aoff, &As[j * 4096 + wv * 1024]);
#pragma unroll
        for (int j = 0; j < 4; ++j)
            gload_lds16(bBase[j] + boff, &Bs[j * 4096 + wv * 1024]);
        __syncthreads();

#pragma unroll
        for (int kk = 0; kk < 2; ++kk) {
            intx4 af[4], bf[4];
            int kc = kk * 4 + (lane >> 4);          // 16B k-chunk index 0..7
#pragma unroll
            for (int im = 0; im < 4; ++im) {
                int rA = wm * 64 + im * 16 + (lane & 15);
                af[im] = *(const intx4*)&As[rA * BKB + ((kc ^ (rA & 7)) << 4)];
            }
#pragma unroll
            for (int in = 0; in < 4; ++in) {
                int rB = wn * 64 + in * 16 + (lane & 15);
                bf[in] = *(const intx4*)&Bs[rB * BKB + ((kc ^ (rB & 7)) << 4)];
            }
#pragma unroll
            for (int im = 0; im < 4; ++im)
#pragma unroll
                for (int in = 0; in < 4; ++in)
                    acc[im][in] = __builtin_amdgcn_mfma_i32_16x16x64_i8(
                        af[im], bf[in], acc[im][in], 0, 0, 0);
        }
        __syncthreads();
    }

    // epilogue: C/D layout col=lane&15, row=(lane>>4)*4+reg (shape-determined)
    int colBase = nt * 128 + wn * 64 + (lane & 15);
    int rowBase = mt * 128 + wm * 64 + (lane >> 4) * 4;
#pragma unroll
    for (int in = 0; in < 4; ++in) {
        int o = colBase + in * 16;
        float s1 = 0.f, s2 = 0.f;
#pragma unroll
        for (int im = 0; im < 4; ++im) {
            int m0 = rowBase + im * 16;
#pragma unroll
            for (int rg = 0; rg < 4; ++rg) {
                int vi = acc[im][in][rg];               // exact integer count
                y[(size_t)(m0 + rg) * COUT + o] = (short)vi;
                float v = (float)vi;
                s1 += v;
                s2 += v * v;
            }
        }
        s1 += __shfl_xor(s1, 16); s2 += __shfl_xor(s2, 16);
        s1 += __shfl_xor(s1, 32); s2 += __shfl_xor(s2, 32);
        if ((lane >> 4) == 0) {
            atomicAdd(&bnsum[o], s1);
            atomicAdd(&bnsumsq[o], s2);
        }
    }
}

// ---------------------------------------------------------------------------
// Kernel 5: fold BN into per-channel (g, c): out = relu(g*s + c)
// ---------------------------------------------------------------------------
__global__ void coeff(const float* __restrict__ bnsum, const float* __restrict__ bnsumsq,
                      const float* __restrict__ scale, const float* __restrict__ gamma,
                      const float* __restrict__ beta, float* __restrict__ kg,
                      float* __restrict__ kc) {
    int o = threadIdx.x;
    float mean = bnsum[o] * (1.f / (float)NPIX);
    float var  = fmaxf(bnsumsq[o] * (1.f / (float)NPIX) - mean * mean, 0.f);
    float sc   = scale[o];
    float inv  = rsqrtf(sc * sc * var + 1e-5f);
    float g    = gamma[o] * sc * inv;
    kg[o] = g;
    kc[o] = beta[o] - mean * g;
}

// ---------------------------------------------------------------------------
// Kernel 6: int16 NHWC -> fp32 NCHW transpose + affine + relu.
// Phase 1: short8 16B loads; phase 2: float4 16B stores. Stride-65 LDS.
// ---------------------------------------------------------------------------
__global__ __launch_bounds__(256) void bn_out(const short* __restrict__ y,
                                              const float* __restrict__ kg,
                                              const float* __restrict__ kc,
                                              float* __restrict__ out) {
    __shared__ float lds[64 * 65];   // [pix][ch], stride 65
    int p0 = blockIdx.x * 64;
    int o0 = blockIdx.y * 64;
    int n  = blockIdx.z;
    int t  = threadIdx.x;
    int cch = t & 7;
    float g[8], c[8];
#pragma unroll
    for (int e = 0; e < 8; ++e) {
        g[e] = kg[o0 + cch * 8 + e];
        c[e] = kc[o0 + cch * 8 + e];
    }
    const short* yb = y + ((size_t)n * HW + p0) * COUT + o0;
#pragma unroll
    for (int j = 0; j < 2; ++j) {
        int pi = (t >> 3) + 32 * j;
        short8 sv = *(const short8*)&yb[(size_t)pi * COUT + cch * 8];
#pragma unroll
        for (int e = 0; e < 8; ++e)
            lds[pi * 65 + cch * 8 + e] = fmaxf(g[e] * (float)sv[e] + c[e], 0.f);
    }
    __syncthreads();
    float* ob = out + ((size_t)n * COUT + o0) * HW + p0;
    int pq = t & 15;       // 16 float4 = 64 pixels
    int ch = t >> 4;       // 16 channels per round
#pragma unroll
    for (int r = 0; r < 4; ++r) {
        int cr = ch + 16 * r;
        floatx4 v;
#pragma unroll
        for (int e = 0; e < 4; ++e) v[e] = lds[(pq * 4 + e) * 65 + cr];
        *(floatx4*)&ob[(size_t)cr * HW + pq * 4] = v;
    }
}

// ---------------------------------------------------------------------------
extern "C" void kernel_launch(void* const* d_in, const int* in_sizes, int n_in,
                              void* d_out, int out_size, void* d_ws, size_t ws_size,
                              hipStream_t stream) {
    const float* x     = (const float*)d_in[0];   // [32,256,56,56]
    const float* w     = (const float*)d_in[1];   // [256,256,3,3]
    const float* gamma = (const float*)d_in[2];   // [256]
    const float* beta  = (const float*)d_in[3];   // [256]
    float* out = (float*)d_out;

    char* ws = (char*)d_ws;
    size_t off = 0;
    i8* xs = (i8*)(ws + off);    off += (size_t)BATCH * PPIX * CIN;                // 27.6 MB
    i8* wg = (i8*)(ws + off);    off += (size_t)COUT * KTOT;                       // 0.59 MB
    short* y = (short*)(ws + off); off += (size_t)NPIX * COUT * sizeof(short);     // 51.4 MB
    float* scale   = (float*)(ws + off); off += 1024;
    float* bnsum   = (float*)(ws + off); off += 1024;
    float* bnsumsq = (float*)(ws + off); off += 1024;
    float* kg      = (float*)(ws + off); off += 1024;
    float* kc      = (float*)(ws + off); off += 1024;

    hipLaunchKernelGGL(prep_w, dim3(COUT), dim3(256), 0, stream, w, wg, scale, bnsum, bnsumsq);
    hipLaunchKernelGGL(zero_border, dim3(BATCH * PH), dim3(256), 0, stream, xs);
    hipLaunchKernelGGL(binarize, dim3(HW / 64, CIN / 64, BATCH), dim3(256), 0, stream, x, xs);
    hipLaunchKernelGGL(conv_gemm, dim3(NPIX / 128, 2), dim3(256), 0, stream,
                       xs, wg, y, bnsum, bnsumsq);
    hipLaunchKernelGGL(coeff, dim3(1), dim3(256), 0, stream,
                       bnsum, bnsumsq, scale, gamma, beta, kg, kc);
    hipLaunchKernelGGL(bn_out, dim3(HW / 64, COUT / 64, BATCH), dim3(256), 0, stream,
                       y, kg, kc, out);
}

// Round 5
// 307.713 us; speedup vs baseline: 1.4612x; 1.0885x over previous
//
#include <hip/hip_runtime.h>
#include <stdint.h>
#include <type_traits>

// ---------------- problem constants ----------------
#define CIN   256
#define COUT  256
#define HH    56
#define WW    56
#define HW    3136          // 56*56
#define BATCH 32
#define NPIX  (BATCH*HW)    // 100352 = 784 * 128 exactly
#define PH    58
#define PW    58
#define PPIX  (PH*PW)       // 3364
#define KTOT  2304          // 9 taps * 256 cin
#define BKB   128           // K-block in bytes (i8 elems) = half a tap
#define NKIT  (KTOT/BKB)    // 18

typedef int8_t  i8;
typedef int     intx4  __attribute__((ext_vector_type(4)));
typedef int8_t  i8x16  __attribute__((ext_vector_type(16)));
typedef short   short8 __attribute__((ext_vector_type(8)));
typedef float   floatx4 __attribute__((ext_vector_type(4)));

// -------- global->LDS 16B async copy (offset arg MUST be 0: it shifts the
// LDS destination too — see IntrinsicsAMDGPU.td; R4 failed on this) ---------
__device__ __forceinline__ void gload_lds16(const i8* g, void* lds_base) {
    __builtin_amdgcn_global_load_lds(
        (const __attribute__((address_space(1))) void*)g,
        (__attribute__((address_space(3))) void*)lds_base,
        16, 0, 0);
}

// ---------------------------------------------------------------------------
// Kernel 1: weight prep. scale[o]=mean|w[o]|; wg[o][t*256+i]=sign(w) as int8.
// Also zero-inits BN-stat accumulators (ws is poisoned each launch).
// ---------------------------------------------------------------------------
__global__ __launch_bounds__(256) void prep_w(const float* __restrict__ w,
                                              i8* __restrict__ wg,
                                              float* __restrict__ scale,
                                              float* __restrict__ bnsum,
                                              float* __restrict__ bnsumsq) {
    int o = blockIdx.x;
    int i = threadIdx.x;
    const float* wrow = w + (size_t)o * KTOT + (size_t)i * 9;   // OIHW
    float asum = 0.f;
#pragma unroll
    for (int t = 0; t < 9; ++t) {
        float v = wrow[t];
        asum += fabsf(v);
        wg[(size_t)o * KTOT + t * CIN + i] = (v > 0.f) ? (i8)1 : ((v < 0.f) ? (i8)(-1) : (i8)0);
    }
    for (int off = 32; off > 0; off >>= 1) asum += __shfl_down(asum, off);
    __shared__ float red[4];
    if ((threadIdx.x & 63) == 0) red[threadIdx.x >> 6] = asum;
    __syncthreads();
    if (threadIdx.x == 0) {
        scale[o]   = (red[0] + red[1] + red[2] + red[3]) * (1.f / (float)KTOT);
        bnsum[o]   = 0.f;
        bnsumsq[o] = 0.f;
    }
}

// ---------------------------------------------------------------------------
// Kernel 2: zero the 1-pixel border of the padded NHWC int8 sign tensor.
// ---------------------------------------------------------------------------
__global__ __launch_bounds__(256) void zero_border(i8* __restrict__ xs) {
    int n  = blockIdx.x / PH;
    int pr = blockIdx.x % PH;
    int* row = (int*)(xs + ((size_t)n * PPIX + (size_t)pr * PW) * CIN);
    if (pr == 0 || pr == PH - 1) {
        for (int idx = threadIdx.x; idx < PW * CIN / 4; idx += 256) row[idx] = 0;
    } else {
        if (threadIdx.x < 64)       row[threadIdx.x] = 0;                       // col 0
        else if (threadIdx.x < 128) row[(PW - 1) * (CIN / 4) + threadIdx.x - 64] = 0; // col 57
    }
}

// ---------------------------------------------------------------------------
// Kernel 3: binarize + NCHW->padded-NHWC transpose, int8 out.
// grid (49, 4, 32): 64-pixel x 64-cin tiles. Dword-packed LDS, stride 17.
// ---------------------------------------------------------------------------
__global__ __launch_bounds__(256) void binarize(const float* __restrict__ x,
                                                i8* __restrict__ xs) {
    __shared__ int lds[64 * 17];   // [pix][cinquad], stride 17 dwords
    int p0 = blockIdx.x * 64;
    int c0 = blockIdx.y * 64;
    int n  = blockIdx.z;
    const float* xin = x + (size_t)n * CIN * HW;
    int t   = threadIdx.x;
    int pix = t & 63;
#pragma unroll
    for (int r = 0; r < 4; ++r) {
        int cq = (t >> 6) + 4 * r;            // cin quad 0..15
        int packed = 0;
#pragma unroll
        for (int e = 0; e < 4; ++e) {
            float v = xin[(size_t)(c0 + cq * 4 + e) * HW + p0 + pix];
            int s = (v > 0.f) ? 1 : ((v < 0.f) ? -1 : 0);
            packed |= (s & 0xff) << (8 * e);
        }
        lds[pix * 17 + cq] = packed;
    }
    __syncthreads();
    int cch = t & 3;                           // 16-byte chunk 0..3
    int pi  = t >> 2;                          // pixel 0..63
    int4 v;
    v.x = lds[pi * 17 + cch * 4 + 0];
    v.y = lds[pi * 17 + cch * 4 + 1];
    v.z = lds[pi * 17 + cch * 4 + 2];
    v.w = lds[pi * 17 + cch * 4 + 3];
    int p = p0 + pi;
    int h = p / WW, w = p - (p / WW) * WW;
    *(int4*)&xs[((size_t)n * PPIX + (size_t)(h + 1) * PW + (w + 1)) * CIN
                + c0 + cch * 16] = v;
}

// ---------------------------------------------------------------------------
// Kernel 4: binary conv implicit GEMM, i8 MFMA K=64, BK=128B.
// DOUBLE-BUFFERED (2 x 32 KB LDS), fully unrolled, ONE barrier per K-iter:
//   stage(k): issue loads for k+1 into buf[(k+1)&1]; compute from buf[k&1];
//             __syncthreads().
// The barrier's vmcnt(0) drain only waits on loads issued a full compute
// phase earlier -> drain-free. Buffer b is written in iter k only after the
// barrier ending iter k-1 (its last readers).
// Epilogue: C -> LDS (128x128 int16) -> coalesced short8 NHWC stores +
// per-channel atomic sum/sumsq.
// ---------------------------------------------------------------------------
__global__ __launch_bounds__(256, 2) void conv_gemm(const i8* __restrict__ xs,
                                                    const i8* __restrict__ wg,
                                                    short* __restrict__ y,
                                                    float* __restrict__ bnsum,
                                                    float* __restrict__ bnsumsq) {
    __shared__ __align__(16) i8 smem[65536];   // buf b: As at b*32768, Bs at +16384

    int tid  = threadIdx.x;
    int lane = tid & 63;
    int wv   = tid >> 6;
    int wm   = wv & 1;        // wave row (pixels)
    int wn   = wv >> 1;       // wave col (couts)
    int mt   = blockIdx.x;
    int nt   = blockIdx.y;

    // ---- staging source pointers (XOR-swizzled 16B chunk within 128B row) ----
    int prow = tid >> 3;
    int koff = ((tid ^ (tid >> 3)) & 7) * 16;
    const i8* aP[4];
    const i8* bP[4];
#pragma unroll
    for (int j = 0; j < 4; ++j) {
        int P = mt * 128 + prow + 32 * j;     // global pixel
        int n = P / HW;
        int p = P - n * HW;
        int h = p / WW;
        int w = p - h * WW;
        aP[j] = xs + ((size_t)n * PPIX + (size_t)h * PW + w) * CIN + koff;
        int o = nt * 128 + prow + 32 * j;
        bP[j] = wg + (size_t)o * KTOT + koff;
    }
    i8* aD[2][4];
    i8* bD[2][4];
#pragma unroll
    for (int b = 0; b < 2; ++b)
#pragma unroll
        for (int j = 0; j < 4; ++j) {
            aD[b][j] = smem + b * 32768 + j * 4096 + wv * 1024;
            bD[b][j] = smem + b * 32768 + 16384 + j * 4096 + wv * 1024;
        }

    // ---- fragment read pointers (buffer 0; buffer 1 = +32768) ----
    int l7  = lane & 7;
    int l15 = lane & 15;
    int lhi = lane >> 4;
    int sw0 = ((lhi ^ l7) << 4);              // kk=0 swizzled chunk offset
    int sw1 = sw0 ^ 0x40;                     // kk=1
    const i8* Ard0 = smem + (wm * 64 + l15) * BKB + sw0;
    const i8* Ard1 = smem + (wm * 64 + l15) * BKB + sw1;
    const i8* Brd0 = smem + 16384 + (wn * 64 + l15) * BKB + sw0;
    const i8* Brd1 = smem + 16384 + (wn * 64 + l15) * BKB + sw1;

    intx4 acc[4][4];
#pragma unroll
    for (int im = 0; im < 4; ++im)
#pragma unroll
        for (int in = 0; in < 4; ++in) acc[im][in] = intx4{0, 0, 0, 0};

    // ---- prologue: stage k=0 into buffer 0 ----
#pragma unroll
    for (int j = 0; j < 4; ++j) gload_lds16(aP[j], aD[0][j]);
#pragma unroll
    for (int j = 0; j < 4; ++j) gload_lds16(bP[j], bD[0][j]);
    __syncthreads();

    auto stage = [&](auto KBC) {
        constexpr int KB  = (int)decltype(KBC)::value;
        constexpr int cur = KB & 1;
        if constexpr (KB < NKIT - 1) {
            constexpr int nb  = KB + 1;
            constexpr int nxt = nb & 1;
            constexpr int ao  = (nb / 6) * PW * CIN + (nb % 6) * 128;  // tap row/col
            constexpr int bo  = nb * BKB;
#pragma unroll
            for (int j = 0; j < 4; ++j) gload_lds16(aP[j] + ao, aD[nxt][j]);
#pragma unroll
            for (int j = 0; j < 4; ++j) gload_lds16(bP[j] + bo, bD[nxt][j]);
        }
        constexpr int bufo = cur * 32768;
        intx4 af0[4], bf0[4], af1[4], bf1[4];
#pragma unroll
        for (int im = 0; im < 4; ++im) af0[im] = *(const intx4*)(Ard0 + bufo + im * 2048);
#pragma unroll
        for (int in = 0; in < 4; ++in) bf0[in] = *(const intx4*)(Brd0 + bufo + in * 2048);
#pragma unroll
        for (int im = 0; im < 4; ++im) af1[im] = *(const intx4*)(Ard1 + bufo + im * 2048);
#pragma unroll
        for (int in = 0; in < 4; ++in) bf1[in] = *(const intx4*)(Brd1 + bufo + in * 2048);
#pragma unroll
        for (int im = 0; im < 4; ++im)
#pragma unroll
            for (int in = 0; in < 4; ++in)
                acc[im][in] = __builtin_amdgcn_mfma_i32_16x16x64_i8(
                    af0[im], bf0[in], acc[im][in], 0, 0, 0);
#pragma unroll
        for (int im = 0; im < 4; ++im)
#pragma unroll
            for (int in = 0; in < 4; ++in)
                acc[im][in] = __builtin_amdgcn_mfma_i32_16x16x64_i8(
                    af1[im], bf1[in], acc[im][in], 0, 0, 0);
        __syncthreads();
    };
#define ST(k) stage(std::integral_constant<int, k>{});
    ST(0) ST(1) ST(2) ST(3) ST(4) ST(5) ST(6) ST(7) ST(8)
    ST(9) ST(10) ST(11) ST(12) ST(13) ST(14) ST(15) ST(16) ST(17)
#undef ST

    // ---- epilogue: BN stats from regs + coalesced store via LDS transpose ----
    int colBase = nt * 128 + wn * 64 + l15;            // global cout
    short* yt = (short*)smem;                          // 128 x 128 int16, 32 KB
#pragma unroll
    for (int in = 0; in < 4; ++in) {
        int o = colBase + in * 16;
        float s1 = 0.f, s2 = 0.f;
#pragma unroll
        for (int im = 0; im < 4; ++im) {
            int r0 = wm * 64 + im * 16 + lhi * 4;      // local pixel row
#pragma unroll
            for (int rg = 0; rg < 4; ++rg) {
                int vi = acc[im][in][rg];              // exact integer count
                yt[(r0 + rg) * 128 + wn * 64 + in * 16 + l15] = (short)vi;
                float v = (float)vi;
                s1 += v;
                s2 += v * v;
            }
        }
        s1 += __shfl_xor(s1, 16); s2 += __shfl_xor(s2, 16);
        s1 += __shfl_xor(s1, 32); s2 += __shfl_xor(s2, 32);
        if (lhi == 0) {
            atomicAdd(&bnsum[o], s1);
            atomicAdd(&bnsumsq[o], s2);
        }
    }
    __syncthreads();
    // coalesced NHWC stores: 16 threads x 16B = one 128-cout half-row
#pragma unroll
    for (int pass = 0; pass < 8; ++pass) {
        int p = (tid >> 4) + 16 * pass;
        int c = tid & 15;
        *(short8*)&y[(size_t)(mt * 128 + p) * COUT + nt * 128 + c * 8] =
            *(const short8*)&yt[p * 128 + c * 8];
    }
}

// ---------------------------------------------------------------------------
// Kernel 5: fold BN into per-channel (g, c): out = relu(g*s + c)
// ---------------------------------------------------------------------------
__global__ void coeff(const float* __restrict__ bnsum, const float* __restrict__ bnsumsq,
                      const float* __restrict__ scale, const float* __restrict__ gamma,
                      const float* __restrict__ beta, float* __restrict__ kg,
                      float* __restrict__ kc) {
    int o = threadIdx.x;
    float mean = bnsum[o] * (1.f / (float)NPIX);
    float var  = fmaxf(bnsumsq[o] * (1.f / (float)NPIX) - mean * mean, 0.f);
    float sc   = scale[o];
    float inv  = rsqrtf(sc * sc * var + 1e-5f);
    float g    = gamma[o] * sc * inv;
    kg[o] = g;
    kc[o] = beta[o] - mean * g;
}

// ---------------------------------------------------------------------------
// Kernel 6: int16 NHWC -> fp32 NCHW transpose + affine + relu.
// ---------------------------------------------------------------------------
__global__ __launch_bounds__(256) void bn_out(const short* __restrict__ y,
                                              const float* __restrict__ kg,
                                              const float* __restrict__ kc,
                                              float* __restrict__ out) {
    __shared__ float lds[64 * 65];   // [pix][ch], stride 65
    int p0 = blockIdx.x * 64;
    int o0 = blockIdx.y * 64;
    int n  = blockIdx.z;
    int t  = threadIdx.x;
    int cch = t & 7;
    float g[8], c[8];
#pragma unroll
    for (int e = 0; e < 8; ++e) {
        g[e] = kg[o0 + cch * 8 + e];
        c[e] = kc[o0 + cch * 8 + e];
    }
    const short* yb = y + ((size_t)n * HW + p0) * COUT + o0;
#pragma unroll
    for (int j = 0; j < 2; ++j) {
        int pi = (t >> 3) + 32 * j;
        short8 sv = *(const short8*)&yb[(size_t)pi * COUT + cch * 8];
#pragma unroll
        for (int e = 0; e < 8; ++e)
            lds[pi * 65 + cch * 8 + e] = fmaxf(g[e] * (float)sv[e] + c[e], 0.f);
    }
    __syncthreads();
    float* ob = out + ((size_t)n * COUT + o0) * HW + p0;
    int pq = t & 15;       // 16 float4 = 64 pixels
    int ch = t >> 4;       // 16 channels per round
#pragma unroll
    for (int r = 0; r < 4; ++r) {
        int cr = ch + 16 * r;
        floatx4 v;
#pragma unroll
        for (int e = 0; e < 4; ++e) v[e] = lds[(pq * 4 + e) * 65 + cr];
        *(floatx4*)&ob[(size_t)cr * HW + pq * 4] = v;
    }
}

// ---------------------------------------------------------------------------
extern "C" void kernel_launch(void* const* d_in, const int* in_sizes, int n_in,
                              void* d_out, int out_size, void* d_ws, size_t ws_size,
                              hipStream_t stream) {
    const float* x     = (const float*)d_in[0];   // [32,256,56,56]
    const float* w     = (const float*)d_in[1];   // [256,256,3,3]
    const float* gamma = (const float*)d_in[2];   // [256]
    const float* beta  = (const float*)d_in[3];   // [256]
    float* out = (float*)d_out;

    char* ws = (char*)d_ws;
    size_t off = 0;
    i8* xs = (i8*)(ws + off);    off += (size_t)BATCH * PPIX * CIN;                // 27.6 MB
    i8* wg = (i8*)(ws + off);    off += (size_t)COUT * KTOT;                       // 0.59 MB
    short* y = (short*)(ws + off); off += (size_t)NPIX * COUT * sizeof(short);     // 51.4 MB
    float* scale   = (float*)(ws + off); off += 1024;
    float* bnsum   = (float*)(ws + off); off += 1024;
    float* bnsumsq = (float*)(ws + off); off += 1024;
    float* kg      = (float*)(ws + off); off += 1024;
    float* kc      = (float*)(ws + off); off += 1024;

    hipLaunchKernelGGL(prep_w, dim3(COUT), dim3(256), 0, stream, w, wg, scale, bnsum, bnsumsq);
    hipLaunchKernelGGL(zero_border, dim3(BATCH * PH), dim3(256), 0, stream, xs);
    hipLaunchKernelGGL(binarize, dim3(HW / 64, CIN / 64, BATCH), dim3(256), 0, stream, x, xs);
    hipLaunchKernelGGL(conv_gemm, dim3(NPIX / 128, 2), dim3(256), 0, stream,
                       xs, wg, y, bnsum, bnsumsq);
    hipLaunchKernelGGL(coeff, dim3(1), dim3(256), 0, stream,
                       bnsum, bnsumsq, scale, gamma, beta, kg, kc);
    hipLaunchKernelGGL(bn_out, dim3(HW / 64, COUT / 64, BATCH), dim3(256), 0, stream,
                       y, kg, kc, out);
}